// Round 5
// baseline (347.389 us; speedup 1.0000x reference)
//
#include <hip/hip_runtime.h>
#include <hip/hip_fp16.h>
#include <stdint.h>

// ---------------------------------------------------------------------------
// RuleModel forward. ST-gumbel gate forward == exact one-hot column selector,
// so each h @ gate is a gather with index argmax_i(w[i,j]+g[i,j]).
// Fast path: argmax_part (flat 1676-block grid, ping-pong 2x8-load register
// banks -> >=8 loads always in flight) -> reduce_pairs2 -> forward (4
// rows/block, fp16-packed h). Fallback (small ws): atomic argmax path.
// ---------------------------------------------------------------------------

struct GatePtrs {
    const float* w[12];
    const float* g[12];
};

__device__ __forceinline__ unsigned int sortkey(float f) {
    unsigned int u = __float_as_uint(f);
    return u ^ ((u & 0x80000000u) ? 0xFFFFFFFFu : 0x80000000u);
}

// ---------------- fast path: phase A ---------------------------------------
// partial layout (u64): per layer base pbs[l]; entry (slot, chunk, col) at
// pbs[l] + (slot*ch[l] + chunk)*dout[l] + col. chunk = 16 rows.
// value = (sortkey(best) << 32) | best_row.
// Flat block mapping (no empty blocks):
//   b in [0,260):    layer0, gate=b/65,  chunk=b%65          (dout=1024)
//   b in [260,1032): layer1, gate=u/193, chunk=u%193         (dout=1024)
//   b in [1032,1676):layer2, gate=u/161, chunk=2*(u%161)+sub (dout=512, 2/blk)
__global__ __launch_bounds__(256, 5) void argmax_part(GatePtrs gp,
                                                      unsigned long long* __restrict__ part) {
    int b = blockIdx.x;
    int layer, slot, chunk, dout, ch, pb, din;
    int t = threadIdx.x, c4;
    if (b < 260) {
        layer = 0; slot = b / 65; chunk = b - slot * 65;
        dout = 1024; ch = 65; pb = 0; din = 1026; c4 = t;
    } else if (b < 1032) {
        int u = b - 260;
        layer = 1; slot = u / 193; chunk = u - slot * 193;
        dout = 1024; ch = 193; pb = 266240; din = 3074; c4 = t;
    } else {
        int u = b - 1032;
        layer = 2; slot = u / 161; int pr = u - slot * 161;
        chunk = 2 * pr + (t >> 7); c4 = t & 127;
        dout = 512; ch = 321; pb = 1056768; din = 5122;
        if (chunk >= 321) return;
    }
    int gate = layer * 4 + slot;
    int s4 = dout >> 2;
    int r0 = chunk * 16;
    int n  = min(16, din - r0);               // 16, or 2 on the tail chunk
    const float4* __restrict__ wp = (const float4*)gp.w[gate] + (size_t)r0 * s4 + c4;
    const float4* __restrict__ gq = (const float4*)gp.g[gate] + (size_t)r0 * s4 + c4;
    float bx = -3.4e38f, by = bx, bz = bx, bw = bx;
    int ix = r0, iy = r0, iz = r0, iw = r0;

    auto consume = [&](const float4* wv, const float4* gv, int base) {
        #pragma unroll
        for (int k = 0; k < 4; ++k) {
            int i = base + k;
            float vx = wv[k].x + gv[k].x, vy = wv[k].y + gv[k].y;
            float vz = wv[k].z + gv[k].z, vw = wv[k].w + gv[k].w;
            if (vx > bx) { bx = vx; ix = i; }   // strict > keeps first row
            if (vy > by) { by = vy; iy = i; }
            if (vz > bz) { bz = vz; iz = i; }
            if (vw > bw) { bw = vw; iw = i; }
        }
    };

    if (n == 16) {
        float4 wa[4], ga[4], wb[4], gb[4];
        #pragma unroll
        for (int k = 0; k < 4; ++k) { wa[k] = wp[(size_t)k * s4];       ga[k] = gq[(size_t)k * s4]; }
        #pragma unroll
        for (int k = 0; k < 4; ++k) { wb[k] = wp[(size_t)(4 + k) * s4]; gb[k] = gq[(size_t)(4 + k) * s4]; }
        consume(wa, ga, r0);                   // gen0 (bank A drains, B in flight)
        #pragma unroll
        for (int k = 0; k < 4; ++k) { wa[k] = wp[(size_t)(8 + k) * s4]; ga[k] = gq[(size_t)(8 + k) * s4]; }
        consume(wb, gb, r0 + 4);               // gen1 (A refilling)
        #pragma unroll
        for (int k = 0; k < 4; ++k) { wb[k] = wp[(size_t)(12 + k) * s4]; gb[k] = gq[(size_t)(12 + k) * s4]; }
        consume(wa, ga, r0 + 8);               // gen2 (B refilling)
        consume(wb, gb, r0 + 12);              // gen3
    } else {
        for (int m = 0; m < n; ++m) {
            float4 wv = wp[(size_t)m * s4];
            float4 gv = gq[(size_t)m * s4];
            int i = r0 + m;
            float vx = wv.x + gv.x, vy = wv.y + gv.y;
            float vz = wv.z + gv.z, vw = wv.w + gv.w;
            if (vx > bx) { bx = vx; ix = i; }
            if (vy > by) { by = vy; iy = i; }
            if (vz > bz) { bz = vz; iz = i; }
            if (vw > bw) { bw = vw; iw = i; }
        }
    }

    unsigned long long* dst = part + pb + ((size_t)(slot * ch + chunk)) * dout + 4 * c4;
    ulonglong2 lo, hi;
    lo.x = ((unsigned long long)sortkey(bx) << 32) | (unsigned int)ix;
    lo.y = ((unsigned long long)sortkey(by) << 32) | (unsigned int)iy;
    hi.x = ((unsigned long long)sortkey(bz) << 32) | (unsigned int)iz;
    hi.y = ((unsigned long long)sortkey(bw) << 32) | (unsigned int)iw;
    *(ulonglong2*)dst       = lo;
    *(ulonglong2*)(dst + 2) = hi;
}

// ---------------- fast path: phase B (cooperative reduce) -------------------
// 320 blocks x 256 threads: 32 columns x 8 chunk-lanes. Coalesced reads,
// LDS tree over chunk-lanes. pf[2i+e] = input-e slot index of gate-pair i.
__global__ __launch_bounds__(256) void reduce_pairs2(const unsigned long long* __restrict__ part,
                                                     unsigned short* __restrict__ pf) {
    __shared__ unsigned long long red[256];
    int t = threadIdx.x;
    int k = t >> 5, gi = t & 31;
    int C = blockIdx.x * 32;                  // global col-slot base
    int l, s, g0, half, dout, ch, pb;
    if (C < 4096)      { l = 0; s = C >> 10;          g0 = C & 1023;          half = 1024; dout = 1024; ch = 65;  pb = 0; }
    else if (C < 8192) { l = 1; s = (C - 4096) >> 10; g0 = (C - 4096) & 1023; half = 1024; dout = 1024; ch = 193; pb = 266240; }
    else               { l = 2; s = (C - 8192) >> 9;  g0 = (C - 8192) & 511;  half = 512;  dout = 512;  ch = 321; pb = 1056768; }
    int g = g0 + gi;
    const unsigned long long* __restrict__ p = part + pb + (size_t)(s * ch) * dout + g;
    unsigned long long best = 0;
    for (int c = k; c < ch; c += 8) {
        unsigned long long v = p[(size_t)c * dout];
        if ((unsigned int)(v >> 32) > (unsigned int)(best >> 32)) best = v;
    }
    red[t] = best;
    __syncthreads();
    #pragma unroll
    for (int st = 4; st >= 1; st >>= 1) {
        if (k < st) {
            unsigned long long o = red[t + st * 32];
            if ((unsigned int)(o >> 32) > (unsigned int)(best >> 32)) best = o;
            red[t] = best;
        }
        __syncthreads();
    }
    if (k == 0) {
        int type = s >> 1, e = s & 1;
        int j = 2 * (l * 2048 + type * half + g) + e;
        pf[j] = (unsigned short)best;         // low 16 bits = row index (<5122)
    }
}

// ---------------- fallback: atomic argmax + convert -------------------------
__global__ __launch_bounds__(256) void argmax_atomic(GatePtrs gp,
                                                     unsigned long long* __restrict__ packed) {
    const int dins[3]  = {1026, 3074, 5122};
    const int douts[3] = {1024, 1024, 512};
    const int offs[3]  = {0, 4096, 8192};
    int gate = blockIdx.z, layer = gate >> 2;
    int din = dins[layer], dout = douts[layer];
    int c2 = blockIdx.x * 256 + threadIdx.x;
    int r0 = blockIdx.y * 64;
    if (2 * c2 >= dout || r0 >= din) return;
    int r1 = min(r0 + 64, din);
    const float* __restrict__ w = gp.w[gate];
    const float* __restrict__ g = gp.g[gate];
    float bx = -3.4e38f, by = -3.4e38f;
    int rx = r0, ry = r0;
    #pragma unroll 8
    for (int i = r0; i < r1; ++i) {
        float2 wv = *(const float2*)(w + (size_t)i * dout + 2 * c2);
        float2 gv = *(const float2*)(g + (size_t)i * dout + 2 * c2);
        float vx = wv.x + gv.x, vy = wv.y + gv.y;
        if (vx > bx) { bx = vx; rx = i; }
        if (vy > by) { by = vy; ry = i; }
    }
    unsigned long long* dst = packed + offs[layer] + (gate & 3) * dout + 2 * c2;
    atomicMax(dst, ((unsigned long long)sortkey(bx) << 32)
                   | (unsigned long long)(0xFFFFFFFFu - (unsigned int)rx));
    atomicMax(dst + 1, ((unsigned long long)sortkey(by) << 32)
                   | (unsigned long long)(0xFFFFFFFFu - (unsigned int)ry));
}

__global__ __launch_bounds__(256) void convert_fb(const unsigned long long* __restrict__ packed,
                                                  ushort2* __restrict__ pf) {
    int i = blockIdx.x * 256 + threadIdx.x;
    if (i >= 5120) return;
    int l    = (i < 2048) ? 0 : ((i < 4096) ? 1 : 2);
    int half = (l == 2) ? 512 : 1024;
    int r    = i - l * 2048;
    int type = (r >= half) ? 1 : 0;
    int g    = r - type * half;
    int o1   = l * 4096 + 2 * type * half + g;
    int o2   = o1 + half;
    unsigned int i1 = 0xFFFFFFFFu - (unsigned int)(packed[o1] & 0xFFFFFFFFull);
    unsigned int i2 = 0xFFFFFFFFu - (unsigned int)(packed[o2] & 0xFFFFFFFFull);
    pf[i] = make_ushort2((unsigned short)i1, (unsigned short)i2);
}

// ---------------- forward: 4 rows/block, fp16 packed h ----------------------
__device__ __forceinline__ __half2 bc(unsigned int u) { return __builtin_bit_cast(__half2, u); }
__device__ __forceinline__ unsigned int cb(__half2 h) { return __builtin_bit_cast(unsigned int, h); }

__device__ __forceinline__ uint2 gat(const char* hb, unsigned int s) {
    return *(const uint2*)(hb + (s << 3));
}
__device__ __forceinline__ uint2 andg(uint2 a, uint2 b) {
    return make_uint2(cb(__hmul2(bc(a.x), bc(b.x))), cb(__hmul2(bc(a.y), bc(b.y))));
}
__device__ __forceinline__ uint2 org(uint2 a, uint2 b) {
    __half2 one = __float2half2_rn(1.0f);
    __half2 lo = __hsub2(one, __hmul2(__hsub2(one, bc(a.x)), __hsub2(one, bc(b.x))));
    __half2 hi = __hsub2(one, __hmul2(__hsub2(one, bc(a.y)), __hsub2(one, bc(b.y))));
    return make_uint2(cb(lo), cb(hi));
}

__global__ __launch_bounds__(512) void forward_kernel(const float* __restrict__ x,
                                                      const float* __restrict__ lin_w,
                                                      const ushort2* __restrict__ pairs,
                                                      float* __restrict__ out) {
    __shared__ uint2 h[5122];      // slot s = 4 rows of feature s, fp16 packed
    __shared__ float4 red[8];
    const int t  = threadIdx.x;
    const int r0 = blockIdx.x * 4;
    const char* hb = (const char*)h;

    float xa = x[(size_t)(r0 + 0) * 512 + t];
    float xb = x[(size_t)(r0 + 1) * 512 + t];
    float xc = x[(size_t)(r0 + 2) * 512 + t];
    float xd = x[(size_t)(r0 + 3) * 512 + t];
    ushort2 pa0 = pairs[t], pa1 = pairs[512 + t];
    ushort2 po0 = pairs[1024 + t], po1 = pairs[1536 + t];
    h[t]       = make_uint2(cb(__floats2half2_rn(xa, xb)), cb(__floats2half2_rn(xc, xd)));
    h[512 + t] = make_uint2(cb(__floats2half2_rn(1.f - xa, 1.f - xb)),
                            cb(__floats2half2_rn(1.f - xc, 1.f - xd)));
    if (t == 0) {
        unsigned int o = cb(__float2half2_rn(1.0f));
        h[1024] = make_uint2(o, o);
        h[1025] = make_uint2(0u, 0u);
    }
    __syncthreads();

    {
        uint2 a0 = andg(gat(hb, pa0.x), gat(hb, pa0.y));
        uint2 a1 = andg(gat(hb, pa1.x), gat(hb, pa1.y));
        uint2 o0 = org(gat(hb, po0.x), gat(hb, po0.y));
        uint2 o1 = org(gat(hb, po1.x), gat(hb, po1.y));
        h[1026 + t] = a0; h[1538 + t] = a1;
        h[2050 + t] = o0; h[2562 + t] = o1;
    }
    ushort2 qa0 = pairs[2048 + t], qa1 = pairs[2560 + t];
    ushort2 qo0 = pairs[3072 + t], qo1 = pairs[3584 + t];
    __syncthreads();

    {
        uint2 a0 = andg(gat(hb, qa0.x), gat(hb, qa0.y));
        uint2 a1 = andg(gat(hb, qa1.x), gat(hb, qa1.y));
        uint2 o0 = org(gat(hb, qo0.x), gat(hb, qo0.y));
        uint2 o1 = org(gat(hb, qo1.x), gat(hb, qo1.y));
        h[3074 + t] = a0; h[3586 + t] = a1;
        h[4098 + t] = o0; h[4610 + t] = o1;
    }
    ushort2 za = pairs[4096 + t], zo = pairs[4608 + t];
    float wA = lin_w[t], wO = lin_w[512 + t];
    __syncthreads();

    uint2 cg = andg(gat(hb, za.x), gat(hb, za.y));
    uint2 dg = org(gat(hb, zo.x), gat(hb, zo.y));
    float2 cl = __half22float2(bc(cg.x)), ch2 = __half22float2(bc(cg.y));
    float2 dl = __half22float2(bc(dg.x)), dh = __half22float2(bc(dg.y));
    float4 s;
    s.x = wA * cl.x  + wO * dl.x;
    s.y = wA * cl.y  + wO * dl.y;
    s.z = wA * ch2.x + wO * dh.x;
    s.w = wA * ch2.y + wO * dh.y;

    #pragma unroll
    for (int off = 32; off > 0; off >>= 1) {
        s.x += __shfl_down(s.x, off, 64);
        s.y += __shfl_down(s.y, off, 64);
        s.z += __shfl_down(s.z, off, 64);
        s.w += __shfl_down(s.w, off, 64);
    }
    if ((t & 63) == 0) red[t >> 6] = s;
    __syncthreads();
    if (t == 0) {
        float4 tot = red[0];
        #pragma unroll
        for (int i = 1; i < 8; ++i) {
            tot.x += red[i].x; tot.y += red[i].y;
            tot.z += red[i].z; tot.w += red[i].w;
        }
        *(float4*)(out + r0) = tot;
    }
}

extern "C" void kernel_launch(void* const* d_in, const int* in_sizes, int n_in,
                              void* d_out, int out_size, void* d_ws, size_t ws_size,
                              hipStream_t stream) {
    GatePtrs gp;
    for (int l = 0; l < 3; ++l)
        for (int s = 0; s < 4; ++s) {
            gp.w[l * 4 + s] = (const float*)d_in[l * 8 + s];
            gp.g[l * 4 + s] = (const float*)d_in[l * 8 + 4 + s];
        }
    const float* x     = (const float*)d_in[24];
    const float* lin_w = (const float*)d_in[25];
    float* out = (float*)d_out;

    const size_t partBytes = 1714176ull * 8ull;   // 13,713,408
    if (ws_size >= partBytes + 20480) {
        unsigned long long* part = (unsigned long long*)d_ws;
        unsigned short* pf = (unsigned short*)((char*)d_ws + partBytes);
        argmax_part<<<1676, 256, 0, stream>>>(gp, part);
        reduce_pairs2<<<320, 256, 0, stream>>>(part, pf);
        forward_kernel<<<8192, 512, 0, stream>>>(x, lin_w, (const ushort2*)pf, out);
    } else {
        unsigned long long* packed = (unsigned long long*)d_ws;
        ushort2* pf = (ushort2*)((char*)d_ws + 10240 * 8);
        hipMemsetAsync(d_ws, 0, 10240 * 8, stream);
        dim3 ga(2, 81, 12);
        argmax_atomic<<<ga, 256, 0, stream>>>(gp, packed);
        convert_fb<<<20, 256, 0, stream>>>(packed, pf);
        forward_kernel<<<8192, 512, 0, stream>>>(x, lin_w, (const ushort2*)pf, out);
    }
}